// Round 1
// baseline (24.697 us; speedup 1.0000x reference)
//
#include <hip/hip_runtime.h>
#include <math.h>

#define NELEM 8388608
#define GRID  2048
#define BLOCK 256

// Main reduction: build gammaln tables in LDS, stream elements, accumulate
// per-block partial sums (double) into d_ws (every slot written each call —
// no zero-init dependence, deterministic).
__global__ __launch_bounds__(BLOCK) void loss_main(
    const float* __restrict__ lam,
    const int*   __restrict__ tgt,
    const int*   __restrict__ risk,
    double*      __restrict__ partials)
{
    __shared__ float  lgf_s[256];   // lgamma(t+1) = ln(t!)
    __shared__ float  csum_s[256];  // cumsum_{j<=t} lgamma(j+1)
    __shared__ float  woff[4];
    __shared__ double wsum_d[4];

    const int tid  = threadIdx.x;
    const int lane = tid & 63;
    const int wid  = tid >> 6;

    // ---- build tables: thread i holds lgamma(i+1); inclusive scan over 256 ----
    float v    = lgammaf((float)(tid + 1));
    float scan = v;
    #pragma unroll
    for (int d = 1; d < 64; d <<= 1) {
        float n = __shfl_up(scan, d, 64);
        if (lane >= d) scan += n;
    }
    if (lane == 63) woff[wid] = scan;
    lgf_s[tid] = v;
    __syncthreads();
    float off = 0.f;
    for (int w = 0; w < wid; ++w) off += woff[w];
    csum_s[tid] = scan + off;
    __syncthreads();

    // ---- streaming reduction, 4 elements/thread/iter ----
    const float4* __restrict__ lam4 = (const float4*)lam;
    const int4*   __restrict__ t4   = (const int4*)tgt;
    const int4*   __restrict__ r4   = (const int4*)risk;
    const int nvec = NELEM / 4;

    double acc = 0.0;
    for (int idx = blockIdx.x * BLOCK + tid; idx < nvec; idx += GRID * BLOCK) {
        float4 L = lam4[idx];
        int4   T = t4[idx];
        int4   R = r4[idx];
        float lv[4] = {L.x, L.y, L.z, L.w};
        int   tv[4] = {T.x, T.y, T.z, T.w};
        int   rv[4] = {R.x, R.y, R.z, R.w};
        #pragma unroll
        for (int k = 0; k < 4; ++k) {
            float la = lv[k];
            int   t  = tv[k];
            float tf = (float)t;
            float ll = logf(la);
            float lik = tf * ll - la - lgf_s[t];
            float sv  = (tf + 1.f) * (1.f + la) - ll * tf * (tf + 1.f) * 0.5f + csum_s[t];
            acc += (double)(rv[k] == 1 ? lik : sv);
        }
    }

    // ---- block reduce (double) ----
    #pragma unroll
    for (int d = 32; d > 0; d >>= 1) acc += __shfl_down(acc, d, 64);
    if (lane == 0) wsum_d[wid] = acc;
    __syncthreads();
    if (tid == 0) {
        partials[blockIdx.x] = wsum_d[0] + wsum_d[1] + wsum_d[2] + wsum_d[3];
    }
}

__global__ __launch_bounds__(256) void loss_finalize(
    const double* __restrict__ partials, float* __restrict__ out)
{
    const int tid  = threadIdx.x;
    const int lane = tid & 63;
    const int wid  = tid >> 6;
    __shared__ double ws[4];

    double acc = 0.0;
    for (int i = tid; i < GRID; i += 256) acc += partials[i];
    #pragma unroll
    for (int d = 32; d > 0; d >>= 1) acc += __shfl_down(acc, d, 64);
    if (lane == 0) ws[wid] = acc;
    __syncthreads();
    if (tid == 0) {
        double s = ws[0] + ws[1] + ws[2] + ws[3];
        out[0] = (float)(-s / (double)NELEM);
    }
}

extern "C" void kernel_launch(void* const* d_in, const int* in_sizes, int n_in,
                              void* d_out, int out_size, void* d_ws, size_t ws_size,
                              hipStream_t stream)
{
    const float* lam  = (const float*)d_in[0];
    const int*   tgt  = (const int*)d_in[1];
    const int*   risk = (const int*)d_in[2];
    double* partials  = (double*)d_ws;   // 2048 * 8 B = 16 KB
    float*  out       = (float*)d_out;

    loss_main<<<GRID, BLOCK, 0, stream>>>(lam, tgt, risk, partials);
    loss_finalize<<<1, 256, 0, stream>>>(partials, out);
}